// Round 4
// baseline (526.069 us; speedup 1.0000x reference)
//
#include <hip/hip_runtime.h>

typedef unsigned short u16;
typedef _Float16 f16x8 __attribute__((ext_vector_type(8)));
typedef float f32x4 __attribute__((ext_vector_type(4)));
typedef u16 u16x4 __attribute__((ext_vector_type(4)));

__device__ __forceinline__ u16 f2h(float f) {
    _Float16 h = (_Float16)f;
    return __builtin_bit_cast(u16, h);
}

// ---------------------------------------------------------------- stats ----
__global__ void __launch_bounds__(256) stats_kernel(
    const float* __restrict__ c, const float* __restrict__ s,
    float* __restrict__ mC, float* __restrict__ rC,
    float* __restrict__ mS, float* __restrict__ rS)
{
    const float* src = (blockIdx.y ? s : c) + (size_t)blockIdx.x * 4096;
    int t = threadIdx.x, lane = t & 63, wv = t >> 6;
    const float4* p = (const float4*)src;
    float sum = 0.f, sq = 0.f;
#pragma unroll
    for (int i = 0; i < 4; ++i) {
        float4 v = p[t + 256 * i];
        sum += v.x + v.y + v.z + v.w;
        sq  += v.x * v.x + v.y * v.y + v.z * v.z + v.w * v.w;
    }
#pragma unroll
    for (int m = 1; m < 64; m <<= 1) {
        sum += __shfl_xor(sum, m);
        sq  += __shfl_xor(sq, m);
    }
    __shared__ float sa[4], sb[4];
    if (!lane) { sa[wv] = sum; sb[wv] = sq; }
    __syncthreads();
    if (t == 0) {
        float S = sa[0] + sa[1] + sa[2] + sa[3];
        float Q = sb[0] + sb[1] + sb[2] + sb[3];
        float mean = S * (1.0f / 4096.0f);
        float var = (Q - 4096.0f * mean * mean) * (1.0f / 4095.0f);
        float rstd = rsqrtf(var + 1e-5f);
        if (blockIdx.y) { mS[blockIdx.x] = mean; rS[blockIdx.x] = rstd; }
        else            { mC[blockIdx.x] = mean; rC[blockIdx.x] = rstd; }
    }
}

// ------------------------------------------------------- transpose pack ----
// [B,C,N] fp32 -> [B,N,C] f16. MODE 0: normalized only (dh).
// MODE 2: normalized (dh) + raw (dl) in one pass (for tensor s).
template<int MODE>
__global__ void __launch_bounds__(256) pack_kernel(
    const float* __restrict__ src, const float* __restrict__ mean,
    const float* __restrict__ rstd, u16* __restrict__ dh, u16* __restrict__ dl)
{
    __shared__ float tile[32][33];
    int b = blockIdx.z, n0 = blockIdx.x * 32, c0 = blockIdx.y * 32;
    int tx = threadIdx.x, ty = threadIdx.y;
    const float* sbp = src + ((size_t)b * 512 + c0) * 4096 + n0;
#pragma unroll
    for (int it = 0; it < 4; ++it)
        tile[ty + it * 8][tx] = sbp[(size_t)(ty + it * 8) * 4096 + tx];
    __syncthreads();
    int ch = c0 + tx;
    float mn = mean[b * 512 + ch];
    float rs = rstd[b * 512 + ch];
    size_t obase = ((size_t)b * 4096 + n0) * 512 + c0;
#pragma unroll
    for (int it = 0; it < 4; ++it) {
        int r = ty + it * 8;
        float v = tile[tx][r];
        size_t o = obase + (size_t)r * 512 + tx;
        dh[o] = f2h((v - mn) * rs);
        if (MODE == 2) dl[o] = f2h(v);
    }
}

// ------------------------------------------------------------ wt pack ----
__global__ void __launch_bounds__(256) split_f16(
    const float* __restrict__ src, u16* __restrict__ h, int n)
{
    int i = blockIdx.x * 256 + threadIdx.x;
    if (i < n) h[i] = f2h(src[i]);
}

// ---------------------------------------------------------------- GEMM ----
// C[i,j] = sum_k A[i,k]*B[j,k]  (A:[M,ldk] rowmajor, B:[N,ldk] rowmajor),
// k-loop runs K steps. blockIdx.z offsets A/B/out/resid by aB/bB/oB/rB
// elements (batch index or split-K chunk index). bias nullable.
#define EPI_F32       0
#define EPI_T_F16     1
#define EPI_PLAIN_F16 2
#define EPI_OUT       3

__device__ __forceinline__ void stage_tile(
    const u16* __restrict__ g, int ldk, int i0, int k0, char* tile, int wv, int lane)
{
#pragma unroll
    for (int cc = 0; cc < 4; ++cc) {
        int chunk = (wv * 4 + cc) * 64 + lane;   // 16B-chunk linear index in tile
        int row  = chunk >> 3;                   // 8 chunks (128B) per row
        int slot = chunk & 7;
        int gc   = slot ^ (row & 7);             // pre-swizzled source column-chunk
        const u16* gp = g + (size_t)(i0 + row) * ldk + (k0 + gc * 8);
        char* lp = tile + (size_t)(wv * 4 + cc) * 1024; // wave-uniform base
        __builtin_amdgcn_global_load_lds(
            (const __attribute__((address_space(1))) unsigned int*)gp,
            (__attribute__((address_space(3))) unsigned int*)lp, 16, 0, 0);
    }
}

template<int EPI>
__global__ void __launch_bounds__(256) gemm_bt(
    const u16* __restrict__ A_, const u16* __restrict__ B_,
    int K, int ldk, const float* __restrict__ bias,
    float* __restrict__ outF_, u16* __restrict__ outH_,
    const float* __restrict__ resid_, int ldo,
    long aB, long bB, long oB, long rB)
{
    __shared__ char smem[32768];
    char* sA = smem;
    char* sB = smem + 16384;

    int bz = blockIdx.z;
    const u16* A  = A_ + (size_t)bz * aB;
    const u16* Bm = B_ + (size_t)bz * bB;

    int i0 = blockIdx.y * 128, j0 = blockIdx.x * 128;
    int tid = threadIdx.x, lane = tid & 63, wv = tid >> 6;
    int wr = wv >> 1, wc = wv & 1;
    int r15 = lane & 15, h4 = lane >> 4;

    f32x4 zero = {0.f, 0.f, 0.f, 0.f};
    f32x4 acc[4][4];
#pragma unroll
    for (int m = 0; m < 4; ++m)
#pragma unroll
        for (int n = 0; n < 4; ++n) acc[m][n] = zero;

    for (int k0 = 0; k0 < K; k0 += 64) {
        stage_tile(A, ldk, i0, k0, sA, wv, lane);
        stage_tile(Bm, ldk, j0, k0, sB, wv, lane);
        asm volatile("s_waitcnt vmcnt(0)" ::: "memory");
        __syncthreads();
#pragma unroll
        for (int ks = 0; ks < 2; ++ks) {
            f16x8 a[4], b[4];
#pragma unroll
            for (int m = 0; m < 4; ++m) {
                int row = wr * 64 + m * 16 + r15;
                int off = row * 128 + (((ks * 4 + h4) ^ (row & 7)) << 4);
                a[m] = *(const f16x8*)(sA + off);
            }
#pragma unroll
            for (int n = 0; n < 4; ++n) {
                int col = wc * 64 + n * 16 + r15;
                int off = col * 128 + (((ks * 4 + h4) ^ (col & 7)) << 4);
                b[n] = *(const f16x8*)(sB + off);
            }
#pragma unroll
            for (int m = 0; m < 4; ++m)
#pragma unroll
                for (int n = 0; n < 4; ++n)
                    acc[m][n] = __builtin_amdgcn_mfma_f32_16x16x32_f16(a[m], b[n], acc[m][n], 0, 0, 0);
        }
        __syncthreads();
    }

    float* outF = outF_ ? outF_ + (size_t)bz * oB : nullptr;
    u16* outH = outH_ ? outH_ + (size_t)bz * oB : nullptr;
    const float* resid = resid_ ? resid_ + (size_t)bz * rB : nullptr;

#pragma unroll
    for (int m = 0; m < 4; ++m)
#pragma unroll
        for (int n = 0; n < 4; ++n) {
            int ibase = i0 + wr * 64 + m * 16 + h4 * 4;
            int j = j0 + wc * 64 + n * 16 + r15;
#pragma unroll
            for (int r = 0; r < 4; ++r) {
                int i = ibase + r;
                float v = acc[m][n][r];
                if constexpr (EPI == EPI_T_F16 || EPI == EPI_PLAIN_F16 || EPI == EPI_OUT)
                    if (bias) v += bias[i];
                if constexpr (EPI == EPI_F32) {
                    outF[(size_t)i * ldo + j] = v;
                } else if constexpr (EPI == EPI_T_F16) {
                    outH[(size_t)j * ldo + i] = f2h(v);
                } else if constexpr (EPI == EPI_PLAIN_F16) {
                    outH[(size_t)i * ldo + j] = f2h(v);
                } else { // EPI_OUT
                    outF[(size_t)i * ldo + j] = v + resid[(size_t)i * ldo + j];
                }
            }
        }
}

// ------------------------------------------------------------- softmax ----
// one block per row; L row fp32[4096] -> P row f16[4096] (softmax over m)
__global__ void __launch_bounds__(256) softmax_kernel(
    const float* __restrict__ L, u16* __restrict__ P)
{
    int row = blockIdx.x;
    int t = threadIdx.x, lane = t & 63, wv = t >> 6;
    const float4* src = (const float4*)(L + (size_t)row * 4096);
    float4 v[4];
    float mx = -3.4e38f;
#pragma unroll
    for (int i = 0; i < 4; ++i) {
        v[i] = src[t + 256 * i];
        mx = fmaxf(mx, fmaxf(fmaxf(v[i].x, v[i].y), fmaxf(v[i].z, v[i].w)));
    }
#pragma unroll
    for (int m = 1; m < 64; m <<= 1) mx = fmaxf(mx, __shfl_xor(mx, m));
    __shared__ float sM[4], sS[4];
    if (!lane) sM[wv] = mx;
    __syncthreads();
    mx = fmaxf(fmaxf(sM[0], sM[1]), fmaxf(sM[2], sM[3]));
    float e[16];
    float sum = 0.f;
#pragma unroll
    for (int i = 0; i < 4; ++i) {
        e[4 * i + 0] = __expf(v[i].x - mx);
        e[4 * i + 1] = __expf(v[i].y - mx);
        e[4 * i + 2] = __expf(v[i].z - mx);
        e[4 * i + 3] = __expf(v[i].w - mx);
        sum += e[4 * i + 0] + e[4 * i + 1] + e[4 * i + 2] + e[4 * i + 3];
    }
#pragma unroll
    for (int m = 1; m < 64; m <<= 1) sum += __shfl_xor(sum, m);
    if (!lane) sS[wv] = sum;
    __syncthreads();
    sum = sS[0] + sS[1] + sS[2] + sS[3];
    float inv = 1.0f / sum;
    u16* prow = P + (size_t)row * 4096;
#pragma unroll
    for (int i = 0; i < 4; ++i) {
        u16x4 o;
        o[0] = f2h(e[4 * i + 0] * inv);
        o[1] = f2h(e[4 * i + 1] * inv);
        o[2] = f2h(e[4 * i + 2] * inv);
        o[3] = f2h(e[4 * i + 3] * inv);
        *(u16x4*)(prow + (size_t)(t + 256 * i) * 4) = o;
    }
}

// -------------------------------------------------------------- launch ----
extern "C" void kernel_launch(void* const* d_in, const int* in_sizes, int n_in,
                              void* d_out, int out_size, void* d_ws, size_t ws_size,
                              hipStream_t stream)
{
    const float* c   = (const float*)d_in[0];
    const float* s   = (const float*)d_in[1];
    const float* x   = (const float*)d_in[2];
    const float* c_w = (const float*)d_in[3];
    const float* c_b = (const float*)d_in[4];
    const float* s_w = (const float*)d_in[5];
    const float* s_b = (const float*)d_in[6];
    const float* i_w = (const float*)d_in[7];
    const float* i_b = (const float*)d_in[8];
    const float* o_w = (const float*)d_in[9];
    const float* o_b = (const float*)d_in[10];
    float* out = (float*)d_out;
    char* ws = (char*)d_ws;

    const int B = 4, C = 512, N = 4096;
    const size_t NC = (size_t)N * C;          // 2097152
    const size_t W2 = (size_t)C * C;          // 262144
    const size_t NN = (size_t)N * N;          // 16777216

    size_t off = 0;
    auto alloc = [&](size_t bytes) { size_t o = off; off += (bytes + 255) & ~(size_t)255; return o; };

    size_t o_meanC = alloc((size_t)B * C * 4);
    size_t o_rstdC = alloc((size_t)B * C * 4);
    size_t o_meanS = alloc((size_t)B * C * 4);
    size_t o_rstdS = alloc((size_t)B * C * 4);
    size_t o_cw = alloc(W2 * 2);
    size_t o_sw = alloc(W2 * 2);
    size_t o_iw = alloc(W2 * 2);
    size_t o_ow = alloc(W2 * 2);
    size_t o_cfT = alloc(B * NC * 2);
    size_t o_sfT = alloc(B * NC * 2);
    size_t o_xf  = alloc(B * NC * 2);
    size_t o_P   = alloc(B * NN * 2);        // P for ALL batches (134 MB)
    size_t o_E   = alloc(3 * B * NC * 2 / 4 * 4); // 50.3MB region, multi-use:
    // phase1: cnT|snT|sT packs; phase2: L half-logits fp32 (33.6MB) at E+0;
    // phase3: ofT [B,N,C] f16 (16.8MB) at E+0 (L dead).

    if (ws_size < off) { // not enough scratch: bail (will fail check loudly)
        hipMemsetAsync(d_out, 0, (size_t)out_size * 4, stream);
        return;
    }

    float* meanC = (float*)(ws + o_meanC);
    float* rstdC = (float*)(ws + o_rstdC);
    float* meanS = (float*)(ws + o_meanS);
    float* rstdS = (float*)(ws + o_rstdS);
    u16* cw = (u16*)(ws + o_cw);
    u16* sw = (u16*)(ws + o_sw);
    u16* iw = (u16*)(ws + o_iw);
    u16* ow = (u16*)(ws + o_ow);
    u16* cfT = (u16*)(ws + o_cfT);
    u16* sfT = (u16*)(ws + o_sfT);
    u16* xf  = (u16*)(ws + o_xf);
    u16* Pb  = (u16*)(ws + o_P);
    u16* cnT = (u16*)(ws + o_E);
    u16* snT = cnT + B * NC;
    u16* sT  = snT + B * NC;
    float* Lbuf = (float*)(ws + o_E);        // 2048*4096 fp32 over cnT+snT
    u16* ofT = (u16*)(ws + o_E);             // over dead L

    // 1) instance-norm stats
    stats_kernel<<<dim3(B * C, 2), 256, 0, stream>>>(c, s, meanC, rstdC, meanS, rstdS);
    // 2) packs: c -> cnT (norm); s -> snT (norm) + sT (raw) in one pass
    pack_kernel<0><<<dim3(N / 32, C / 32, B), dim3(32, 8), 0, stream>>>(c, meanC, rstdC, cnT, nullptr);
    pack_kernel<2><<<dim3(N / 32, C / 32, B), dim3(32, 8), 0, stream>>>(s, meanS, rstdS, snT, sT);
    // 3) weight packs
    split_f16<<<dim3((int)(W2 / 256)), 256, 0, stream>>>(c_w, cw, (int)W2);
    split_f16<<<dim3((int)(W2 / 256)), 256, 0, stream>>>(s_w, sw, (int)W2);
    split_f16<<<dim3((int)(W2 / 256)), 256, 0, stream>>>(i_w, iw, (int)W2);
    split_f16<<<dim3((int)(W2 / 256)), 256, 0, stream>>>(o_w, ow, (int)W2);
    // 4) cf = c_w @ cn + c_b  -> cfT [B,N,C] f16
    gemm_bt<EPI_T_F16><<<dim3(32, 4, B), 256, 0, stream>>>(
        cw, cnT, 512, 512, c_b, nullptr, cfT, nullptr, 512,
        0, (long)NC, (long)NC, 0);
    // 5) sf = s_w @ sn + s_b  -> sfT
    gemm_bt<EPI_T_F16><<<dim3(32, 4, B), 256, 0, stream>>>(
        sw, snT, 512, 512, s_b, nullptr, sfT, nullptr, 512,
        0, (long)NC, (long)NC, 0);
    // 6) xf = i_w @ s + i_b   -> xf f16 [B,C,N]   (consumes sT; E free after)
    gemm_bt<EPI_PLAIN_F16><<<dim3(32, 4, B), 256, 0, stream>>>(
        iw, sT, 512, 512, i_b, nullptr, xf, nullptr, 4096,
        0, (long)NC, (long)NC, 0);
    // 7) logits+softmax per (batch, row-half); P kept for all batches
    for (int b = 0; b < B; ++b) {
        for (int h = 0; h < 2; ++h) {
            gemm_bt<EPI_F32><<<dim3(32, 16, 1), 256, 0, stream>>>(
                cfT + (size_t)b * NC + (size_t)h * 2048 * 512,
                sfT + (size_t)b * NC,
                512, 512, nullptr, Lbuf, nullptr, nullptr, 4096, 0, 0, 0, 0);
            softmax_kernel<<<dim3(2048), 256, 0, stream>>>(
                Lbuf, Pb + (size_t)b * NN + (size_t)h * 2048 * 4096);
        }
    }
    // 8) of[c,n] = sum_m xf[c,m] * P[n,m] — ALL batches, one dispatch,
    //    no split-K; writes ofT [B,N,C] f16 directly (L region is dead).
    gemm_bt<EPI_T_F16><<<dim3(32, 4, B), 256, 0, stream>>>(
        xf, Pb, 4096, 4096, nullptr, nullptr, ofT, nullptr, 512,
        (long)NC, (long)NN, (long)NC, 0);
    // 9) out = x + o_w @ of + o_b
    gemm_bt<EPI_OUT><<<dim3(32, 4, B), 256, 0, stream>>>(
        ow, ofT, 512, 512, o_b, out, nullptr, x, 4096,
        0, (long)NC, (long)NC, (long)NC);
}

// Round 5
// 457.839 us; speedup vs baseline: 1.1490x; 1.1490x over previous
//
#include <hip/hip_runtime.h>

typedef unsigned short u16;
typedef _Float16 f16x8 __attribute__((ext_vector_type(8)));
typedef float f32x4 __attribute__((ext_vector_type(4)));
typedef u16 u16x8v __attribute__((ext_vector_type(8)));

__device__ __forceinline__ u16 f2h(float f) {
    _Float16 h = (_Float16)f;
    return __builtin_bit_cast(u16, h);
}
__device__ __forceinline__ float h2f(u16 u) {
    return (float)__builtin_bit_cast(_Float16, u);
}

// ---------------------------------------------------------------- stats ----
__global__ void __launch_bounds__(256) stats_kernel(
    const float* __restrict__ c, const float* __restrict__ s,
    float* __restrict__ mC, float* __restrict__ rC,
    float* __restrict__ mS, float* __restrict__ rS)
{
    const float* src = (blockIdx.y ? s : c) + (size_t)blockIdx.x * 4096;
    int t = threadIdx.x, lane = t & 63, wv = t >> 6;
    const float4* p = (const float4*)src;
    float sum = 0.f, sq = 0.f;
#pragma unroll
    for (int i = 0; i < 4; ++i) {
        float4 v = p[t + 256 * i];
        sum += v.x + v.y + v.z + v.w;
        sq  += v.x * v.x + v.y * v.y + v.z * v.z + v.w * v.w;
    }
#pragma unroll
    for (int m = 1; m < 64; m <<= 1) {
        sum += __shfl_xor(sum, m);
        sq  += __shfl_xor(sq, m);
    }
    __shared__ float sa[4], sb[4];
    if (!lane) { sa[wv] = sum; sb[wv] = sq; }
    __syncthreads();
    if (t == 0) {
        float S = sa[0] + sa[1] + sa[2] + sa[3];
        float Q = sb[0] + sb[1] + sb[2] + sb[3];
        float mean = S * (1.0f / 4096.0f);
        float var = (Q - 4096.0f * mean * mean) * (1.0f / 4095.0f);
        float rstd = rsqrtf(var + 1e-5f);
        if (blockIdx.y) { mS[blockIdx.x] = mean; rS[blockIdx.x] = rstd; }
        else            { mC[blockIdx.x] = mean; rC[blockIdx.x] = rstd; }
    }
}

// ------------------------------------------------------- transpose pack ----
// MODE 0: dh = transposed normalized [B,N,C] f16.
// MODE 3: dh = transposed normalized; dl = NATURAL raw [B,C,N] f16.
template<int MODE>
__global__ void __launch_bounds__(256) pack_kernel(
    const float* __restrict__ src, const float* __restrict__ mean,
    const float* __restrict__ rstd, u16* __restrict__ dh, u16* __restrict__ dl)
{
    __shared__ float tile[32][33];
    int b = blockIdx.z, n0 = blockIdx.x * 32, c0 = blockIdx.y * 32;
    int tx = threadIdx.x, ty = threadIdx.y;
    const float* sbp = src + ((size_t)b * 512 + c0) * 4096 + n0;
#pragma unroll
    for (int it = 0; it < 4; ++it) {
        int cc = ty + it * 8;
        float v = sbp[(size_t)cc * 4096 + tx];
        tile[cc][tx] = v;
        if (MODE == 3)
            dl[((size_t)b * 512 + c0 + cc) * 4096 + n0 + tx] = f2h(v);
    }
    __syncthreads();
    int ch = c0 + tx;
    float mn = mean[b * 512 + ch];
    float rs = rstd[b * 512 + ch];
    size_t obase = ((size_t)b * 4096 + n0) * 512 + c0;
#pragma unroll
    for (int it = 0; it < 4; ++it) {
        int r = ty + it * 8;
        dh[obase + (size_t)r * 512 + tx] = f2h((tile[tx][r] - mn) * rs);
    }
}

// ------------------------------------------------------------ wt packs ----
__global__ void __launch_bounds__(256) split_f16(
    const float* __restrict__ src, u16* __restrict__ h, int n)
{
    int i = blockIdx.x * 256 + threadIdx.x;
    if (i < n) h[i] = f2h(src[i]);
}

// wT[c][k] = w[k][c], 512x512 fp32 -> f16
__global__ void __launch_bounds__(256) tpack512(
    const float* __restrict__ w, u16* __restrict__ wT)
{
    __shared__ float tile[32][33];
    int c0 = blockIdx.x * 32, k0 = blockIdx.y * 32;
    int tx = threadIdx.x, ty = threadIdx.y;
#pragma unroll
    for (int it = 0; it < 4; ++it) {
        int kk = ty + it * 8;
        tile[kk][tx] = w[(size_t)(k0 + kk) * 512 + c0 + tx];
    }
    __syncthreads();
#pragma unroll
    for (int it = 0; it < 4; ++it) {
        int r = ty + it * 8;
        wT[(size_t)(c0 + r) * 512 + k0 + tx] = f2h(tile[tx][r]);
    }
}

// v[o] = o_b[o] + sum_k o_w[o,k] * i_b[k]   (fp32 inputs)
__global__ void __launch_bounds__(256) vbias_kernel(
    const float* __restrict__ o_w, const float* __restrict__ i_b,
    const float* __restrict__ o_b, float* __restrict__ v)
{
    __shared__ float ib[512];
    int t = threadIdx.x;
    ib[t] = i_b[t]; ib[t + 256] = i_b[t + 256];
    __syncthreads();
    int o = blockIdx.x * 256 + t;
    float acc = o_b[o];
    const float* row = o_w + (size_t)o * 512;
    for (int k = 0; k < 512; ++k) acc += row[k] * ib[k];
    v[o] = acc;
}

// ---------------------------------------------------------------- GEMM ----
// C[i,j] = sum_k A[i,k]*B[j,k]  (A:[M,ldk] rowmajor, B:[N,ldk] rowmajor),
// K steps of the k loop. z decomposes as batch = z/zdiv, chunk = z%zdiv:
//   A += batch*aBatch + chunk*aChunk;  B += batch*bBatch + chunk*bChunk;
//   out += z*oZ; resid += z*rZ.   bias nullable.
#define EPI_F32       0
#define EPI_T_F16     1
#define EPI_PLAIN_F16 2
#define EPI_OUT       3

__device__ __forceinline__ void stage_tile(
    const u16* __restrict__ g, int ldk, int i0, int k0, char* tile, int wv, int lane)
{
#pragma unroll
    for (int cc = 0; cc < 4; ++cc) {
        int chunk = (wv * 4 + cc) * 64 + lane;   // 16B-chunk linear index in tile
        int row  = chunk >> 3;                   // 8 chunks (128B) per row
        int slot = chunk & 7;
        int gc   = slot ^ (row & 7);             // pre-swizzled source column-chunk
        const u16* gp = g + (size_t)(i0 + row) * ldk + (k0 + gc * 8);
        char* lp = tile + (size_t)(wv * 4 + cc) * 1024; // wave-uniform base
        __builtin_amdgcn_global_load_lds(
            (const __attribute__((address_space(1))) unsigned int*)gp,
            (__attribute__((address_space(3))) unsigned int*)lp, 16, 0, 0);
    }
}

template<int EPI>
__global__ void __launch_bounds__(256) gemm_bt(
    const u16* __restrict__ A_, const u16* __restrict__ B_,
    int K, int ldk, const float* __restrict__ bias,
    float* __restrict__ outF_, u16* __restrict__ outH_,
    const float* __restrict__ resid_, int ldo, int zdiv,
    long aBatch, long aChunk, long bBatch, long bChunk, long oZ, long rZ)
{
    __shared__ char smem[32768];
    char* sA = smem;
    char* sB = smem + 16384;

    int bz = blockIdx.z;
    int batch = bz / zdiv, chunk = bz % zdiv;
    const u16* A  = A_ + (size_t)batch * aBatch + (size_t)chunk * aChunk;
    const u16* Bm = B_ + (size_t)batch * bBatch + (size_t)chunk * bChunk;

    int i0 = blockIdx.y * 128, j0 = blockIdx.x * 128;
    int tid = threadIdx.x, lane = tid & 63, wv = tid >> 6;
    int wr = wv >> 1, wc = wv & 1;
    int r15 = lane & 15, h4 = lane >> 4;

    f32x4 zero = {0.f, 0.f, 0.f, 0.f};
    f32x4 acc[4][4];
#pragma unroll
    for (int m = 0; m < 4; ++m)
#pragma unroll
        for (int n = 0; n < 4; ++n) acc[m][n] = zero;

    for (int k0 = 0; k0 < K; k0 += 64) {
        stage_tile(A, ldk, i0, k0, sA, wv, lane);
        stage_tile(Bm, ldk, j0, k0, sB, wv, lane);
        asm volatile("s_waitcnt vmcnt(0)" ::: "memory");
        __syncthreads();
#pragma unroll
        for (int ks = 0; ks < 2; ++ks) {
            f16x8 a[4], b[4];
#pragma unroll
            for (int m = 0; m < 4; ++m) {
                int row = wr * 64 + m * 16 + r15;
                int off = row * 128 + (((ks * 4 + h4) ^ (row & 7)) << 4);
                a[m] = *(const f16x8*)(sA + off);
            }
#pragma unroll
            for (int n = 0; n < 4; ++n) {
                int col = wc * 64 + n * 16 + r15;
                int off = col * 128 + (((ks * 4 + h4) ^ (col & 7)) << 4);
                b[n] = *(const f16x8*)(sB + off);
            }
#pragma unroll
            for (int m = 0; m < 4; ++m)
#pragma unroll
                for (int n = 0; n < 4; ++n)
                    acc[m][n] = __builtin_amdgcn_mfma_f32_16x16x32_f16(a[m], b[n], acc[m][n], 0, 0, 0);
        }
        __syncthreads();
    }

    float* outF = outF_ ? outF_ + (size_t)bz * oZ : nullptr;
    u16* outH = outH_ ? outH_ + (size_t)bz * oZ : nullptr;
    const float* resid = resid_ ? resid_ + (size_t)bz * rZ : nullptr;

#pragma unroll
    for (int m = 0; m < 4; ++m)
#pragma unroll
        for (int n = 0; n < 4; ++n) {
            int ibase = i0 + wr * 64 + m * 16 + h4 * 4;
            int j = j0 + wc * 64 + n * 16 + r15;
#pragma unroll
            for (int r = 0; r < 4; ++r) {
                int i = ibase + r;
                float v = acc[m][n][r];
                if constexpr (EPI == EPI_T_F16 || EPI == EPI_PLAIN_F16 || EPI == EPI_OUT)
                    if (bias) v += bias[i];
                if constexpr (EPI == EPI_F32) {
                    outF[(size_t)i * ldo + j] = v;
                } else if constexpr (EPI == EPI_T_F16) {
                    outH[(size_t)j * ldo + i] = f2h(v);
                } else if constexpr (EPI == EPI_PLAIN_F16) {
                    outH[(size_t)i * ldo + j] = f2h(v);
                } else { // EPI_OUT
                    outF[(size_t)i * ldo + j] = v + resid[(size_t)i * ldo + j];
                }
            }
        }
}

// ------------------------------------------------------ softmax (f16) ----
// one block per row; L row f16[4096] -> P f16 IN PLACE (softmax over m)
__global__ void __launch_bounds__(256) softmax16(u16* __restrict__ LP)
{
    u16x8v* row = (u16x8v*)(LP + (size_t)blockIdx.x * 4096);
    int t = threadIdx.x, lane = t & 63, wv = t >> 6;
    u16x8v ca = row[t], cb = row[t + 256];
    float va[8], vb[8];
    float mx = -3.4e38f;
#pragma unroll
    for (int i = 0; i < 8; ++i) {
        va[i] = h2f(ca[i]); vb[i] = h2f(cb[i]);
        mx = fmaxf(mx, fmaxf(va[i], vb[i]));
    }
#pragma unroll
    for (int m = 1; m < 64; m <<= 1) mx = fmaxf(mx, __shfl_xor(mx, m));
    __shared__ float sM[4], sS[4];
    if (!lane) sM[wv] = mx;
    __syncthreads();
    mx = fmaxf(fmaxf(sM[0], sM[1]), fmaxf(sM[2], sM[3]));
    float sum = 0.f;
#pragma unroll
    for (int i = 0; i < 8; ++i) {
        va[i] = __expf(va[i] - mx);
        vb[i] = __expf(vb[i] - mx);
        sum += va[i] + vb[i];
    }
#pragma unroll
    for (int m = 1; m < 64; m <<= 1) sum += __shfl_xor(sum, m);
    if (!lane) sS[wv] = sum;
    __syncthreads();
    sum = sS[0] + sS[1] + sS[2] + sS[3];
    float inv = 1.0f / sum;
    u16x8v oa, ob;
#pragma unroll
    for (int i = 0; i < 8; ++i) {
        oa[i] = f2h(va[i] * inv);
        ob[i] = f2h(vb[i] * inv);
    }
    row[t] = oa; row[t + 256] = ob;
}

// ------------------------------------------------ split-K reduce + T ------
// part: [8][512][4096] fp32 (planes 2b,2b+1 belong to batch b);
// out: smT [B][4096][512] f16
__global__ void __launch_bounds__(256) reduceT_kernel(
    const float* __restrict__ part, u16* __restrict__ smT)
{
    __shared__ float tile[32][33];
    const size_t PLANE = 512 * 4096;
    int n0 = blockIdx.x * 32, c0 = blockIdx.y * 32, b = blockIdx.z;
    int tx = threadIdx.x, ty = threadIdx.y;
    const float* p0 = part + (size_t)(2 * b) * PLANE;
#pragma unroll
    for (int it = 0; it < 4; ++it) {
        int cc = ty + it * 8;
        size_t idx = (size_t)(c0 + cc) * 4096 + n0 + tx;
        tile[cc][tx] = p0[idx] + p0[idx + PLANE];
    }
    __syncthreads();
    size_t obase = ((size_t)b * 4096 + n0) * 512 + c0;
#pragma unroll
    for (int it = 0; it < 4; ++it) {
        int r = ty + it * 8;
        smT[obase + (size_t)r * 512 + tx] = f2h(tile[tx][r]);
    }
}

// -------------------------------------------------------------- launch ----
extern "C" void kernel_launch(void* const* d_in, const int* in_sizes, int n_in,
                              void* d_out, int out_size, void* d_ws, size_t ws_size,
                              hipStream_t stream)
{
    const float* c   = (const float*)d_in[0];
    const float* s   = (const float*)d_in[1];
    const float* x   = (const float*)d_in[2];
    const float* c_w = (const float*)d_in[3];
    const float* c_b = (const float*)d_in[4];
    const float* s_w = (const float*)d_in[5];
    const float* s_b = (const float*)d_in[6];
    const float* i_w = (const float*)d_in[7];
    const float* i_b = (const float*)d_in[8];
    const float* o_w = (const float*)d_in[9];
    const float* o_b = (const float*)d_in[10];
    float* out = (float*)d_out;
    char* ws = (char*)d_ws;

    const int B = 4, C = 512, N = 4096;
    const size_t NC = (size_t)N * C;          // 2097152
    const size_t W2 = (size_t)C * C;          // 262144
    const size_t NN = (size_t)N * N;          // 16777216
    const size_t PLANE = (size_t)C * N;       // 2097152 (fp32 partial plane)

    size_t off = 0;
    auto alloc = [&](size_t bytes) { size_t o = off; off += (bytes + 255) & ~(size_t)255; return o; };

    size_t o_meanC = alloc((size_t)B * C * 4);
    size_t o_rstdC = alloc((size_t)B * C * 4);
    size_t o_meanS = alloc((size_t)B * C * 4);
    size_t o_rstdS = alloc((size_t)B * C * 4);
    size_t o_cw  = alloc(W2 * 2);
    size_t o_sw  = alloc(W2 * 2);
    size_t o_ow  = alloc(W2 * 2);
    size_t o_iwT = alloc(W2 * 2);
    size_t o_W   = alloc(W2 * 2);            // W = o_w @ i_w, f16
    size_t o_v   = alloc((size_t)C * 4);     // v = o_w@i_b + o_b, fp32
    size_t o_cfT = alloc(B * NC * 2);        // reused as smT after logits
    size_t o_sfT = alloc(B * NC * 2);
    size_t o_sR  = alloc(B * NC * 2);        // raw s f16 [B,C,N]
    size_t o_L   = alloc(B * NN * 2);        // f16 logits -> P in place (134MB)
                                             // phase1: hosts cnT|snT packs
    size_t o_pt  = alloc(8 * PLANE * 4);     // split-K2 fp32 partials (67MB)

    if (ws_size < off) { // not enough scratch: bail (will fail check loudly)
        hipMemsetAsync(d_out, 0, (size_t)out_size * 4, stream);
        return;
    }

    float* meanC = (float*)(ws + o_meanC);
    float* rstdC = (float*)(ws + o_rstdC);
    float* meanS = (float*)(ws + o_meanS);
    float* rstdS = (float*)(ws + o_rstdS);
    u16* cw  = (u16*)(ws + o_cw);
    u16* sw  = (u16*)(ws + o_sw);
    u16* ow  = (u16*)(ws + o_ow);
    u16* iwT = (u16*)(ws + o_iwT);
    u16* Wf  = (u16*)(ws + o_W);
    float* vb = (float*)(ws + o_v);
    u16* cfT = (u16*)(ws + o_cfT);
    u16* sfT = (u16*)(ws + o_sfT);
    u16* sR  = (u16*)(ws + o_sR);
    u16* Lp  = (u16*)(ws + o_L);
    float* part = (float*)(ws + o_pt);
    u16* cnT = (u16*)(ws + o_L);             // packs alias over L (dead before logits)
    u16* snT = cnT + B * NC;
    u16* smT = cfT;                          // smT aliases cfT (dead after logits)

    // 1) instance-norm stats
    stats_kernel<<<dim3(B * C, 2), 256, 0, stream>>>(c, s, meanC, rstdC, meanS, rstdS);
    // 2) packs: c -> cnT (norm,T); s -> snT (norm,T) + sR (raw, natural)
    pack_kernel<0><<<dim3(N / 32, C / 32, B), dim3(32, 8), 0, stream>>>(c, meanC, rstdC, cnT, nullptr);
    pack_kernel<3><<<dim3(N / 32, C / 32, B), dim3(32, 8), 0, stream>>>(s, meanS, rstdS, snT, sR);
    // 3) weight packs + fused W,v
    split_f16<<<dim3((int)(W2 / 256)), 256, 0, stream>>>(c_w, cw, (int)W2);
    split_f16<<<dim3((int)(W2 / 256)), 256, 0, stream>>>(s_w, sw, (int)W2);
    split_f16<<<dim3((int)(W2 / 256)), 256, 0, stream>>>(o_w, ow, (int)W2);
    tpack512<<<dim3(16, 16), dim3(32, 8), 0, stream>>>(i_w, iwT);
    vbias_kernel<<<dim3(2), 256, 0, stream>>>(o_w, i_b, o_b, vb);
    // W = o_w @ i_w  (f16, [512,512])
    gemm_bt<EPI_PLAIN_F16><<<dim3(4, 4, 1), 256, 0, stream>>>(
        ow, iwT, 512, 512, nullptr, nullptr, Wf, nullptr, 512, 1,
        0, 0, 0, 0, 0, 0);
    // 4) cf = c_w @ cn + c_b -> cfT [B,N,C];  sf likewise
    gemm_bt<EPI_T_F16><<<dim3(32, 4, B), 256, 0, stream>>>(
        cw, cnT, 512, 512, c_b, nullptr, cfT, nullptr, 512, 1,
        0, 0, (long)NC, 0, (long)NC, 0);
    gemm_bt<EPI_T_F16><<<dim3(32, 4, B), 256, 0, stream>>>(
        sw, snT, 512, 512, s_b, nullptr, sfT, nullptr, 512, 1,
        0, 0, (long)NC, 0, (long)NC, 0);
    // 5) logits all-batch: L[b,n,m] f16 (writes over pack region, now dead)
    gemm_bt<EPI_PLAIN_F16><<<dim3(32, 32, B), 256, 0, stream>>>(
        cfT, sfT, 512, 512, nullptr, nullptr, Lp, nullptr, 4096, 1,
        (long)NC, 0, (long)NC, 0, (long)NN, 0);
    // 6) softmax in place: P = softmax_m(L)
    softmax16<<<dim3(B * N), 256, 0, stream>>>(Lp);
    // 7) PV all-batch split-K2: sm[c,n] = sum_m s[c,m] P[n,m]
    //    z: batch = z/2, chunk = z%2 (k-offset 2048). fp32 partials.
    gemm_bt<EPI_F32><<<dim3(32, 4, 8), 256, 0, stream>>>(
        sR, Lp, 2048, 4096, nullptr, part, nullptr, nullptr, 4096, 2,
        (long)NC, 2048L, (long)NN, 2048L, (long)PLANE, 0);
    // 8) reduce partials + transpose -> smT [B,N,C] f16 (over dead cfT)
    reduceT_kernel<<<dim3(128, 16, B), dim3(32, 8), 0, stream>>>(part, smT);
    // 9) out = x + W @ sm + v
    gemm_bt<EPI_OUT><<<dim3(32, 4, B), 256, 0, stream>>>(
        Wf, smT, 512, 512, vb, out, nullptr, x, 4096, 1,
        0, 0, (long)NC, 0, (long)NC, (long)NC);
}